// Round 1
// baseline (3135.389 us; speedup 1.0000x reference)
//
#include <hip/hip_runtime.h>

// PlayerPerformanceGNN: 2-layer GCN (32->16->8) + mean-pool + linear (8->5)
// N=1M nodes, E=16M edges, G=10k graphs.
// Round 0: correctness-first scatter-atomic implementation.
//   - edge aggregation: thread per (edge,feature); 16/8-lane groups give one
//     contiguous 64B/32B gather of h[src] and same-cacheline atomics on agg[dst]
//   - norm_e = dis[src]*dis[dst] computed on the fly (dis is 4 MB, L2-resident)
//   - workspace ~132 MB, ping-pong A/B buffers reused between conv1 and conv2

namespace {

constexpr int F_IN = 32, F_H1 = 16, F_H2 = 8, N_CLS = 5;

__global__ void k_deg(const int* __restrict__ dst, float* __restrict__ deg, int E) {
  int e = blockIdx.x * blockDim.x + threadIdx.x;
  if (e < E) atomicAdd(&deg[dst[e]], 1.0f);
}

__global__ void k_dis(float* __restrict__ d, int N) {
  int i = blockIdx.x * blockDim.x + threadIdx.x;
  if (i < N) d[i] = rsqrtf(d[i] + 1.0f);
}

// h1 = x @ W1   (thread per node; W1 staged in LDS; row loads via float4)
__global__ void k_mm1(const float* __restrict__ x, const float* __restrict__ W,
                      float* __restrict__ h, int N) {
  __shared__ float w[F_IN * F_H1];
  for (int k = threadIdx.x; k < F_IN * F_H1; k += blockDim.x) w[k] = W[k];
  __syncthreads();
  int i = blockIdx.x * blockDim.x + threadIdx.x;
  if (i >= N) return;
  const float4* xr = reinterpret_cast<const float4*>(x + (size_t)i * F_IN);
  float acc[F_H1];
#pragma unroll
  for (int f = 0; f < F_H1; ++f) acc[f] = 0.f;
#pragma unroll
  for (int k4 = 0; k4 < F_IN / 4; ++k4) {
    float4 v = xr[k4];
    float vv[4] = {v.x, v.y, v.z, v.w};
#pragma unroll
    for (int j = 0; j < 4; ++j) {
      const float* wr = &w[(k4 * 4 + j) * F_H1];
#pragma unroll
      for (int f = 0; f < F_H1; ++f) acc[f] = fmaf(vv[j], wr[f], acc[f]);
    }
  }
  float4* hr = reinterpret_cast<float4*>(h + (size_t)i * F_H1);
#pragma unroll
  for (int q = 0; q < F_H1 / 4; ++q)
    hr[q] = make_float4(acc[q * 4], acc[q * 4 + 1], acc[q * 4 + 2], acc[q * 4 + 3]);
}

// h2 = out1 @ W2  (16 -> 8)
__global__ void k_mm2(const float* __restrict__ in, const float* __restrict__ W,
                      float* __restrict__ h, int N) {
  __shared__ float w[F_H1 * F_H2];
  for (int k = threadIdx.x; k < F_H1 * F_H2; k += blockDim.x) w[k] = W[k];
  __syncthreads();
  int i = blockIdx.x * blockDim.x + threadIdx.x;
  if (i >= N) return;
  const float4* xr = reinterpret_cast<const float4*>(in + (size_t)i * F_H1);
  float acc[F_H2];
#pragma unroll
  for (int f = 0; f < F_H2; ++f) acc[f] = 0.f;
#pragma unroll
  for (int k4 = 0; k4 < F_H1 / 4; ++k4) {
    float4 v = xr[k4];
    float vv[4] = {v.x, v.y, v.z, v.w};
#pragma unroll
    for (int j = 0; j < 4; ++j) {
      const float* wr = &w[(k4 * 4 + j) * F_H2];
#pragma unroll
      for (int f = 0; f < F_H2; ++f) acc[f] = fmaf(vv[j], wr[f], acc[f]);
    }
  }
  float4* hr = reinterpret_cast<float4*>(h + (size_t)i * F_H2);
#pragma unroll
  for (int q = 0; q < F_H2 / 4; ++q)
    hr[q] = make_float4(acc[q * 4], acc[q * 4 + 1], acc[q * 4 + 2], acc[q * 4 + 3]);
}

// scatter aggregation: agg[dst*F+f] += h[src*F+f] * dis[src]*dis[dst]
template <int F>
__global__ void k_edge(const int* __restrict__ src, const int* __restrict__ dst,
                       const float* __restrict__ dis, const float* __restrict__ h,
                       float* __restrict__ agg, int total) {
  int gid = blockIdx.x * blockDim.x + threadIdx.x;
  if (gid >= total) return;
  int e = gid / F, f = gid % F;
  int s = src[e], d = dst[e];
  float nw = dis[s] * dis[d];
  atomicAdd(&agg[d * F + f], h[s * F + f] * nw);
}

// out = relu(agg + h*dis^2 + b), in place into agg
template <int F>
__global__ void k_combine(const float* __restrict__ h, const float* __restrict__ dis,
                          const float* __restrict__ b, float* __restrict__ agg,
                          int total) {
  int gid = blockIdx.x * blockDim.x + threadIdx.x;
  if (gid >= total) return;
  int i = gid / F, f = gid % F;
  float di = dis[i];
  float v = agg[gid] + h[gid] * di * di + b[f];
  agg[gid] = fmaxf(v, 0.f);
}

// conv2 combine + relu + pooled-sum atomics (batch sorted -> good locality)
__global__ void k_combine_pool(const float* __restrict__ h2, const float* __restrict__ agg2,
                               const float* __restrict__ dis, const float* __restrict__ b,
                               const int* __restrict__ batch, float* __restrict__ pooled,
                               float* __restrict__ cnts, int total) {
  int gid = blockIdx.x * blockDim.x + threadIdx.x;
  if (gid >= total) return;
  int i = gid >> 3, f = gid & 7;
  float di = dis[i];
  float v = fmaxf(agg2[gid] + h2[gid] * di * di + b[f], 0.f);
  int g = batch[i];
  atomicAdd(&pooled[g * F_H2 + f], v);
  if (f == 0) atomicAdd(&cnts[g], 1.0f);
}

// out[g,c] = (pooled[g,:]/max(cnt,1)) @ Wl[:,c] + bl[c]
__global__ void k_final(const float* __restrict__ pooled, const float* __restrict__ cnts,
                        const float* __restrict__ Wl, const float* __restrict__ bl,
                        float* __restrict__ out, int total) {
  int gid = blockIdx.x * blockDim.x + threadIdx.x;
  if (gid >= total) return;
  int g = gid / N_CLS, c = gid % N_CLS;
  float s = 0.f;
#pragma unroll
  for (int f = 0; f < F_H2; ++f) s += pooled[g * F_H2 + f] * Wl[f * N_CLS + c];
  out[gid] = s / fmaxf(cnts[g], 1.f) + bl[c];
}

}  // namespace

extern "C" void kernel_launch(void* const* d_in, const int* in_sizes, int n_in,
                              void* d_out, int out_size, void* d_ws, size_t ws_size,
                              hipStream_t stream) {
  const float* x   = (const float*)d_in[0];
  const int* ei    = (const int*)d_in[1];
  const int* batch = (const int*)d_in[2];
  // d_in[3] = num_graphs scalar (unused; dims fixed)
  const float* W1 = (const float*)d_in[4];
  const float* b1 = (const float*)d_in[5];
  const float* W2 = (const float*)d_in[6];
  const float* b2 = (const float*)d_in[7];
  const float* Wl = (const float*)d_in[8];
  const float* bl = (const float*)d_in[9];

  const int N = in_sizes[0] / F_IN;   // 1,000,000
  const int E = in_sizes[1] / 2;      // 16,000,000
  const int G = out_size / N_CLS;     // 10,000
  const int* src = ei;
  const int* dstp = ei + E;

  float* ws = (float*)d_ws;
  float* dis    = ws;                       // N
  float* A      = ws + N;                   // N*16  (h1; later h2 [N*8] + agg2 [N*8])
  float* B      = A + (size_t)N * F_H1;     // N*16  (agg1 -> out1)
  float* h2     = A;
  float* agg2   = A + (size_t)N * F_H2;
  float* pooled = B + (size_t)N * F_H1;     // G*8
  float* cnts   = pooled + (size_t)G * F_H2;// G

  const int BLK = 256;

  // zero accumulators (ws is poisoned 0xAA before every call)
  hipMemsetAsync(dis, 0, (size_t)N * sizeof(float), stream);
  hipMemsetAsync(B, 0, (size_t)N * F_H1 * sizeof(float), stream);
  hipMemsetAsync(pooled, 0, ((size_t)G * F_H2 + G) * sizeof(float), stream);

  // degrees + rsqrt
  k_deg<<<(E + BLK - 1) / BLK, BLK, 0, stream>>>(dstp, dis, E);
  k_dis<<<(N + BLK - 1) / BLK, BLK, 0, stream>>>(dis, N);

  // conv1
  k_mm1<<<(N + BLK - 1) / BLK, BLK, 0, stream>>>(x, W1, A, N);
  {
    int total = E * F_H1;  // 256M
    k_edge<F_H1><<<(unsigned)((long long)(total + BLK - 1) / BLK), BLK, 0, stream>>>(
        src, dstp, dis, A, B, total);
  }
  k_combine<F_H1><<<(N * F_H1 + BLK - 1) / BLK, BLK, 0, stream>>>(A, dis, b1, B, N * F_H1);

  // conv2 (h1 in A dead after combine1 -> reuse A for h2 + agg2)
  hipMemsetAsync(agg2, 0, (size_t)N * F_H2 * sizeof(float), stream);
  k_mm2<<<(N + BLK - 1) / BLK, BLK, 0, stream>>>(B, W2, h2, N);
  {
    int total = E * F_H2;  // 128M
    k_edge<F_H2><<<(unsigned)((long long)(total + BLK - 1) / BLK), BLK, 0, stream>>>(
        src, dstp, dis, h2, agg2, total);
  }
  k_combine_pool<<<(N * F_H2 + BLK - 1) / BLK, BLK, 0, stream>>>(
      h2, agg2, dis, b2, batch, pooled, cnts, N * F_H2);

  // head
  k_final<<<(G * N_CLS + BLK - 1) / BLK, BLK, 0, stream>>>(
      pooled, cnts, Wl, bl, (float*)d_out, G * N_CLS);
}